// Round 11
// baseline (179.173 us; speedup 1.0000x reference)
//
#include <hip/hip_runtime.h>

#define NSEG 16
#define CIN 64
#define COUT 128
#define BN_EPS 1e-5f

typedef float vf4 __attribute__((ext_vector_type(4)));

// ---- index dtype hedge: reference says int64 but JAX default-x64-off makes int32.
// Viewing buffer as int32: element N-1 is 15 (last sorted value) if int32,
// but 0 (high word of element (N-1)/2, N-1 odd) if int64.
__device__ __forceinline__ bool idx_is64(const void* p, int N) {
    return ((const int*)p)[N - 1] == 0;
}
__device__ __forceinline__ int load_idx(const void* p, long long i, bool is64) {
    return is64 ? (int)((const long long*)p)[i] : ((const int*)p)[i];
}

// ws layout:
//   [0,              NSEG*CIN)           float seg_sum[16][64]   (4 KB)
//   [NSEG*CIN,       NSEG*CIN+NSEG*COUT) float h_final[16][128]  (8 KB)

__global__ __launch_bounds__(256) void k_zero(float* __restrict__ seg_sum) {
    for (int i = threadIdx.x; i < NSEG * CIN; i += 256) seg_sum[i] = 0.0f;
}

// Segment-sum: contiguous chunk per block; sorted indices => ~1-2 segments/chunk.
// Thread owns one float4 column-slice (q4) and walks rows with stride 16.
// ONLY change vs measured-best R1: nontemporal feature loads (feat is read
// exactly once; keep it out of L2/LLC so idx stays cached for gather).
__global__ __launch_bounds__(256) void k_segsum(const float* __restrict__ feat,
                                                const void* __restrict__ idx,
                                                float* __restrict__ seg_sum,
                                                int N, int rows_per_blk) {
    __shared__ float acc_lds[NSEG * CIN];
    const int tid = threadIdx.x;
    for (int i = tid; i < NSEG * CIN; i += 256) acc_lds[i] = 0.0f;
    __syncthreads();

    const bool is64 = idx_is64(idx, N);
    const int q4 = (tid & 15) * 4;        // float offset within row (16B aligned)
    const int row0 = blockIdx.x * rows_per_blk;
    const int row_end = min(row0 + rows_per_blk, N);

    vf4 acc = {0.f, 0.f, 0.f, 0.f};
    int cur = -1;
    for (int r = row0 + (tid >> 4); r < row_end; r += 16) {
        const int s = load_idx(idx, r, is64);
        if (s != cur) {
            if (cur >= 0) {
                atomicAdd(&acc_lds[cur * CIN + q4 + 0], acc.x);
                atomicAdd(&acc_lds[cur * CIN + q4 + 1], acc.y);
                atomicAdd(&acc_lds[cur * CIN + q4 + 2], acc.z);
                atomicAdd(&acc_lds[cur * CIN + q4 + 3], acc.w);
            }
            acc = (vf4){0.f, 0.f, 0.f, 0.f};
            cur = s;
        }
        const vf4 v = __builtin_nontemporal_load(
            (const vf4*)(feat + (size_t)r * CIN + q4));
        acc += v;
    }
    if (cur >= 0) {
        atomicAdd(&acc_lds[cur * CIN + q4 + 0], acc.x);
        atomicAdd(&acc_lds[cur * CIN + q4 + 1], acc.y);
        atomicAdd(&acc_lds[cur * CIN + q4 + 2], acc.z);
        atomicAdd(&acc_lds[cur * CIN + q4 + 3], acc.w);
    }
    __syncthreads();
    // Block flush: skip zeros (untouched segments) -> ~128 global atomics/block.
    for (int i = tid; i < NSEG * CIN; i += 256) {
        const float v = acc_lds[i];
        if (v != 0.0f) atomicAdd(&seg_sum[i], v);
    }
}

// Single block: counts via binary search, pooled mean, 16x64 @ 64x128 dot,
// BatchNorm (biased variance over 16), ReLU -> h_final[16][128].
__global__ __launch_bounds__(256) void k_mlp(const float* __restrict__ seg_sum,
                                             const void* __restrict__ idx, int N,
                                             const float* __restrict__ W,
                                             const float* __restrict__ gamma,
                                             const float* __restrict__ beta,
                                             float* __restrict__ h_final) {
    __shared__ float pooled[NSEG * CIN];     // 4 KB
    __shared__ float h_lds[NSEG * COUT];     // 8 KB
    __shared__ float cnt[NSEG];
    __shared__ float scale_s[COUT], bias_s[COUT];
    __shared__ int bnd[NSEG + 1];
    const int tid = threadIdx.x;
    const bool is64 = idx_is64(idx, N);

    if (tid <= NSEG) {
        if (tid == 0) bnd[0] = 0;
        else if (tid == NSEG) bnd[NSEG] = N;
        else {
            int lo = 0, hi = N;
            while (lo < hi) {
                const int mid = (lo + hi) >> 1;
                if (load_idx(idx, mid, is64) < tid) lo = mid + 1; else hi = mid;
            }
            bnd[tid] = lo;
        }
    }
    __syncthreads();
    if (tid < NSEG) cnt[tid] = (float)max(bnd[tid + 1] - bnd[tid], 1);
    __syncthreads();
    for (int i = tid; i < NSEG * CIN; i += 256) pooled[i] = seg_sum[i] / cnt[i / CIN];
    __syncthreads();

    const int co = tid & 127;
    const int half = tid >> 7;
    float w[CIN];
    #pragma unroll
    for (int c = 0; c < CIN; c += 4)
        *(vf4*)(w + c) = *(const vf4*)(W + (size_t)co * CIN + c);
    for (int b = half; b < NSEG; b += 2) {
        float a = 0.f;
        #pragma unroll
        for (int c = 0; c < CIN; ++c) a += pooled[b * CIN + c] * w[c];
        h_lds[b * COUT + co] = a;
    }
    __syncthreads();

    if (tid < COUT) {
        float m = 0.f;
        #pragma unroll
        for (int b = 0; b < NSEG; ++b) m += h_lds[b * COUT + tid];
        m *= (1.0f / NSEG);
        float v = 0.f;
        #pragma unroll
        for (int b = 0; b < NSEG; ++b) {
            const float d = h_lds[b * COUT + tid] - m;
            v += d * d;
        }
        v *= (1.0f / NSEG);
        const float sc = gamma[tid] * rsqrtf(v + BN_EPS);
        scale_s[tid] = sc;
        bias_s[tid] = beta[tid] - m * sc;
    }
    __syncthreads();
    for (int b = half; b < NSEG; b += 2) {
        const float hv = h_lds[b * COUT + co] * scale_s[co] + bias_s[co];
        h_final[b * COUT + co] = fmaxf(hv, 0.0f);
    }
}

// Gather: out[n,:] = h_final[idx[n],:]. Grid-stride dense moving window
// (measured best write pattern); NT stores mandatory (R7).
__global__ __launch_bounds__(256) void k_gather(const float* __restrict__ h_final,
                                                const void* __restrict__ idx,
                                                float* __restrict__ out, int N) {
    __shared__ vf4 h4[NSEG * 32];
    const int tid = threadIdx.x;
    for (int i = tid; i < NSEG * 32; i += 256) h4[i] = ((const vf4*)h_final)[i];
    const bool is64 = idx_is64(idx, N);
    __syncthreads();

    vf4* out4 = (vf4*)out;
    const long long total = (long long)N * 32;
    const long long stride = (long long)gridDim.x * 256;
    for (long long i = (long long)blockIdx.x * 256 + tid; i < total; i += stride) {
        const int row = (int)(i >> 5);
        const int q = (int)(i & 31);
        const int s = load_idx(idx, row, is64);
        __builtin_nontemporal_store(h4[s * 32 + q], &out4[i]);
    }
}

extern "C" void kernel_launch(void* const* d_in, const int* in_sizes, int n_in,
                              void* d_out, int out_size, void* d_ws, size_t ws_size,
                              hipStream_t stream) {
    const float* feat  = (const float*)d_in[0];
    const float* W     = (const float*)d_in[1];
    const float* gamma = (const float*)d_in[2];
    const float* beta  = (const float*)d_in[3];
    const void*  idx   = d_in[4];
    const int N = in_sizes[4];

    float* seg_sum = (float*)d_ws;
    float* h_final = (float*)d_ws + NSEG * CIN;

    hipLaunchKernelGGL(k_zero, dim3(1), dim3(256), 0, stream, seg_sum);

    const int NB = 1024;
    const int rows_per_blk = (((N + NB - 1) / NB) + 15) & ~15;
    hipLaunchKernelGGL(k_segsum, dim3(NB), dim3(256), 0, stream,
                       feat, idx, seg_sum, N, rows_per_blk);

    hipLaunchKernelGGL(k_mlp, dim3(1), dim3(256), 0, stream,
                       seg_sum, idx, N, W, gamma, beta, h_final);

    hipLaunchKernelGGL(k_gather, dim3(2048), dim3(256), 0, stream,
                       h_final, idx, (float*)d_out, N);
}

// Round 12
// 155.819 us; speedup vs baseline: 1.1499x; 1.1499x over previous
//
#include <hip/hip_runtime.h>

#define NSEG 16
#define CIN 64
#define COUT 128
#define BN_EPS 1e-5f

typedef float vf4 __attribute__((ext_vector_type(4)));

// ---- index dtype hedge: reference says int64 but JAX default-x64-off makes int32.
// Viewing buffer as int32: element N-1 is 15 (last sorted value) if int32,
// but 0 (high word of element (N-1)/2, N-1 odd) if int64.
__device__ __forceinline__ bool idx_is64(const void* p, int N) {
    return ((const int*)p)[N - 1] == 0;
}
__device__ __forceinline__ int load_idx(const void* p, long long i, bool is64) {
    return is64 ? (int)((const long long*)p)[i] : ((const int*)p)[i];
}

// ws layout:
//   [0,              NSEG*CIN)           float seg_sum[16][64]   (4 KB)
//   [NSEG*CIN,       NSEG*CIN+NSEG*COUT) float h_final[16][128]  (8 KB)

__global__ __launch_bounds__(256) void k_zero(float* __restrict__ seg_sum) {
    for (int i = threadIdx.x; i < NSEG * CIN; i += 256) seg_sum[i] = 0.0f;
}

// Segment-sum: contiguous chunk per block; sorted indices => ~1-2 segments/chunk.
// Thread owns one float4 column-slice (q4) and walks rows with stride 16.
// Plain (cache-retained) loads: LLC keeps ~half of feat across replays (R8/R11).
__global__ __launch_bounds__(256) void k_segsum(const float* __restrict__ feat,
                                                const void* __restrict__ idx,
                                                float* __restrict__ seg_sum,
                                                int N, int rows_per_blk) {
    __shared__ float acc_lds[NSEG * CIN];
    const int tid = threadIdx.x;
    for (int i = tid; i < NSEG * CIN; i += 256) acc_lds[i] = 0.0f;
    __syncthreads();

    const bool is64 = idx_is64(idx, N);
    const int q4 = (tid & 15) * 4;        // float offset within row (16B aligned)
    const int row0 = blockIdx.x * rows_per_blk;
    const int row_end = min(row0 + rows_per_blk, N);

    vf4 acc = {0.f, 0.f, 0.f, 0.f};
    int cur = -1;
    for (int r = row0 + (tid >> 4); r < row_end; r += 16) {
        const int s = load_idx(idx, r, is64);
        if (s != cur) {
            if (cur >= 0) {
                atomicAdd(&acc_lds[cur * CIN + q4 + 0], acc.x);
                atomicAdd(&acc_lds[cur * CIN + q4 + 1], acc.y);
                atomicAdd(&acc_lds[cur * CIN + q4 + 2], acc.z);
                atomicAdd(&acc_lds[cur * CIN + q4 + 3], acc.w);
            }
            acc = (vf4){0.f, 0.f, 0.f, 0.f};
            cur = s;
        }
        const vf4 v = *(const vf4*)(feat + (size_t)r * CIN + q4);
        acc += v;
    }
    if (cur >= 0) {
        atomicAdd(&acc_lds[cur * CIN + q4 + 0], acc.x);
        atomicAdd(&acc_lds[cur * CIN + q4 + 1], acc.y);
        atomicAdd(&acc_lds[cur * CIN + q4 + 2], acc.z);
        atomicAdd(&acc_lds[cur * CIN + q4 + 3], acc.w);
    }
    __syncthreads();
    // Block flush: skip zeros (untouched segments) -> ~128 global atomics/block.
    for (int i = tid; i < NSEG * CIN; i += 256) {
        const float v = acc_lds[i];
        if (v != 0.0f) atomicAdd(&seg_sum[i], v);
    }
}

// Single block: counts via binary search, pooled mean, 16x64 @ 64x128 dot,
// BatchNorm (biased variance over 16), ReLU -> h_final[16][128].
__global__ __launch_bounds__(256) void k_mlp(const float* __restrict__ seg_sum,
                                             const void* __restrict__ idx, int N,
                                             const float* __restrict__ W,
                                             const float* __restrict__ gamma,
                                             const float* __restrict__ beta,
                                             float* __restrict__ h_final) {
    __shared__ float pooled[NSEG * CIN];     // 4 KB
    __shared__ float h_lds[NSEG * COUT];     // 8 KB
    __shared__ float cnt[NSEG];
    __shared__ float scale_s[COUT], bias_s[COUT];
    __shared__ int bnd[NSEG + 1];
    const int tid = threadIdx.x;
    const bool is64 = idx_is64(idx, N);

    if (tid <= NSEG) {
        if (tid == 0) bnd[0] = 0;
        else if (tid == NSEG) bnd[NSEG] = N;
        else {
            int lo = 0, hi = N;
            while (lo < hi) {
                const int mid = (lo + hi) >> 1;
                if (load_idx(idx, mid, is64) < tid) lo = mid + 1; else hi = mid;
            }
            bnd[tid] = lo;
        }
    }
    __syncthreads();
    if (tid < NSEG) cnt[tid] = (float)max(bnd[tid + 1] - bnd[tid], 1);
    __syncthreads();
    for (int i = tid; i < NSEG * CIN; i += 256) pooled[i] = seg_sum[i] / cnt[i / CIN];
    __syncthreads();

    const int co = tid & 127;
    const int half = tid >> 7;
    float w[CIN];
    #pragma unroll
    for (int c = 0; c < CIN; c += 4)
        *(vf4*)(w + c) = *(const vf4*)(W + (size_t)co * CIN + c);
    for (int b = half; b < NSEG; b += 2) {
        float a = 0.f;
        #pragma unroll
        for (int c = 0; c < CIN; ++c) a += pooled[b * CIN + c] * w[c];
        h_lds[b * COUT + co] = a;
    }
    __syncthreads();

    if (tid < COUT) {
        float m = 0.f;
        #pragma unroll
        for (int b = 0; b < NSEG; ++b) m += h_lds[b * COUT + tid];
        m *= (1.0f / NSEG);
        float v = 0.f;
        #pragma unroll
        for (int b = 0; b < NSEG; ++b) {
            const float d = h_lds[b * COUT + tid] - m;
            v += d * d;
        }
        v *= (1.0f / NSEG);
        const float sc = gamma[tid] * rsqrtf(v + BN_EPS);
        scale_s[tid] = sc;
        bias_s[tid] = beta[tid] - m * sc;
    }
    __syncthreads();
    for (int b = half; b < NSEG; b += 2) {
        const float hv = h_lds[b * COUT + co] * scale_s[co] + bias_s[co];
        h_final[b * COUT + co] = fmaxf(hv, 0.0f);
    }
}

// Gather: out[n,:] = h_final[idx[n],:]. Grid-stride dense moving window
// (measured-best write pattern, R6/R9 chunked variants -20-30 us slower);
// NT stores mandatory (R7: plain stores +55 us).
__global__ __launch_bounds__(256) void k_gather(const float* __restrict__ h_final,
                                                const void* __restrict__ idx,
                                                float* __restrict__ out, int N) {
    __shared__ vf4 h4[NSEG * 32];
    const int tid = threadIdx.x;
    for (int i = tid; i < NSEG * 32; i += 256) h4[i] = ((const vf4*)h_final)[i];
    const bool is64 = idx_is64(idx, N);
    __syncthreads();

    vf4* out4 = (vf4*)out;
    const long long total = (long long)N * 32;
    const long long stride = (long long)gridDim.x * 256;
    for (long long i = (long long)blockIdx.x * 256 + tid; i < total; i += stride) {
        const int row = (int)(i >> 5);
        const int q = (int)(i & 31);
        const int s = load_idx(idx, row, is64);
        __builtin_nontemporal_store(h4[s * 32 + q], &out4[i]);
    }
}

extern "C" void kernel_launch(void* const* d_in, const int* in_sizes, int n_in,
                              void* d_out, int out_size, void* d_ws, size_t ws_size,
                              hipStream_t stream) {
    const float* feat  = (const float*)d_in[0];
    const float* W     = (const float*)d_in[1];
    const float* gamma = (const float*)d_in[2];
    const float* beta  = (const float*)d_in[3];
    const void*  idx   = d_in[4];
    const int N = in_sizes[4];

    float* seg_sum = (float*)d_ws;
    float* h_final = (float*)d_ws + NSEG * CIN;

    hipLaunchKernelGGL(k_zero, dim3(1), dim3(256), 0, stream, seg_sum);

    const int NB = 1024;
    const int rows_per_blk = (((N + NB - 1) / NB) + 15) & ~15;
    hipLaunchKernelGGL(k_segsum, dim3(NB), dim3(256), 0, stream,
                       feat, idx, seg_sum, N, rows_per_blk);

    hipLaunchKernelGGL(k_mlp, dim3(1), dim3(256), 0, stream,
                       seg_sum, idx, N, W, gamma, beta, h_final);

    hipLaunchKernelGGL(k_gather, dim3(2048), dim3(256), 0, stream,
                       h_final, idx, (float*)d_out, N);
}